// Round 7
// baseline (367.998 us; speedup 1.0000x reference)
//
#include <hip/hip_runtime.h>
#include <math.h>

#define NEG_BIG (-1e30f)

typedef __attribute__((ext_vector_type(8))) short short8;
typedef __attribute__((ext_vector_type(8))) _Float16 half8;
typedef __attribute__((ext_vector_type(4))) float floatx4;

__device__ __forceinline__ unsigned short f2bf(float x) {
    unsigned u = __float_as_uint(x);
    unsigned r = (u + 0x7fffu + ((u >> 16) & 1u)) >> 16;
    return (unsigned short)r;
}
__device__ __forceinline__ short f2h(float x) {
    _Float16 h = (_Float16)x;
    return __builtin_bit_cast(short, h);
}

// ================= bodies =================

// bonds GEMM: 64 bonds/block, 16 heads, K=512, bf16 (proven numerics, unchanged).
__device__ __forceinline__ void bonds_body(
    int bbid, char* smem,
    const float* __restrict__ fB, const float* __restrict__ fBo,
    const float* __restrict__ Wb_raw, const float* __restrict__ bb_,
    float* __restrict__ bonds, int Nb)
{
    short* feat = (short*)smem;              // [64][136]
    short* wb   = (short*)(smem + 17408);    // [16][512] chunk-swizzled

    const int tid = threadIdx.x;
    const int j0 = bbid * 64;

    for (int c = tid; c < 8192; c += 256) {
        int k = c >> 4, h = c & 15;
        wb[h * 512 + ((((k >> 3) + h) & 63) << 3) + (k & 7)] = (short)f2bf(Wb_raw[c]);
    }

    const int wid = tid >> 6, lane = tid & 63;
    const int quad = lane >> 4, l16 = lane & 15;
    floatx4 acc = (floatx4){0.f, 0.f, 0.f, 0.f};

    const int fr = tid >> 2;
    const int fs = (tid & 3) * 32;
    const int j = j0 + fr;

    for (int k0 = 0; k0 < 512; k0 += 128) {
        float x[32];
        if (j < Nb) {
            const float* p = (k0 < 256) ? (fB + (size_t)j * 256 + k0 + fs)
                                        : (fBo + (size_t)j * 256 + (k0 - 256) + fs);
#pragma unroll
            for (int i = 0; i < 8; i++) {
                float4 v = ((const float4*)p)[i];
                x[i * 4 + 0] = v.x; x[i * 4 + 1] = v.y;
                x[i * 4 + 2] = v.z; x[i * 4 + 3] = v.w;
            }
        } else {
#pragma unroll
            for (int i = 0; i < 32; i++) x[i] = 0.f;
        }
        __syncthreads();
#pragma unroll
        for (int c = 0; c < 4; c++) {
            short8 s;
#pragma unroll
            for (int i = 0; i < 8; i++) s[i] = (short)f2bf(x[c * 8 + i]);
            *(short8*)&feat[fr * 136 + fs + c * 8] = s;
        }
        __syncthreads();
#pragma unroll
        for (int kk = 0; kk < 4; kk++) {
            short8 a = *(const short8*)&feat[(wid * 16 + l16) * 136 + kk * 32 + quad * 8];
            int kchunk = (k0 + kk * 32 + quad * 8) >> 3;
            short8 b = *(const short8*)&wb[l16 * 512 + (((kchunk + l16) & 63) * 8)];
            acc = __builtin_amdgcn_mfma_f32_16x16x32_bf16(a, b, acc, 0, 0, 0);
        }
    }
    float bv = bb_[l16];
#pragma unroll
    for (int r = 0; r < 4; r++) {
        int jj = j0 + wid * 16 + quad * 4 + r;
        if (jj < Nb) bonds[(size_t)jj * 16 + l16] = acc[r] + bv;
    }
}

// scatter: last-update-wins via atomicMax (winner pre-set -1 by memset)
__device__ __forceinline__ void scatter_body(
    int sbid, char* smem,
    const int* __restrict__ b2a, const int* __restrict__ b2revb,
    const int* __restrict__ b_scope, int* __restrict__ winner,
    int Nb, int Bmol)
{
    int* sb = (int*)smem;
    int tid = threadIdx.x;
    if (tid < Bmol) sb[tid] = b_scope[2 * tid];
    __syncthreads();
    int j = sbid * 256 + tid;
    if (j >= Nb) return;
    int lo = 0, hi = Bmol;
    while (lo < hi) { int mid = (lo + hi) >> 1; if (sb[mid] <= j) lo = mid + 1; else hi = mid; }
    int mol = lo - 1; if (mol < 0) mol = 0;
    int p2 = b2a[j];
    int p1 = b2a[b2revb[j]];
    atomicMax(&winner[mol * 16384 + p1 * 128 + p2], j);
}

// atoms GEMM, ZERO-LDS, pure-f16 single product.
// Frag chunk layout (A and B): elem (r,k) at [(rt*64+kq)*128 + l16*8 + e],
// r=rt*16+l16, k=kq*8+e. A wave's frag load = one coalesced 1KB dwordx4 per quarter.
// Numerics: f16 rel err 2^-11, 8x tighter than the passing bf16 bonds path.
__device__ __forceinline__ void atoms_body(
    int abid,
    const int* __restrict__ a_scope,
    const short* __restrict__ AHf, const short* __restrict__ WHf,
    const float* __restrict__ bias, float* __restrict__ out, int Bmol)
{
    const int tid = threadIdx.x;
    const int mol = abid >> 2;
    const int n0 = (abid & 3) * 128;
    const int wid = tid >> 6, lane = tid & 63;
    const int wm = (wid >> 1) * 64, wn = (wid & 1) * 64;
    const int quad = lane >> 4, l16 = lane & 15;
    const int len = a_scope[2 * mol + 1];

    const int laneoff = quad * 128 + l16 * 8;
    const short* __restrict__ Ah = AHf + (size_t)mol * 65536 + (wm >> 4) * 8192 + laneoff;
    const short* __restrict__ Bh = WHf + ((n0 + wn) >> 4) * 8192 + laneoff;

    floatx4 acc[4][4];
#pragma unroll
    for (int i = 0; i < 4; i++)
#pragma unroll
        for (int j = 0; j < 4; j++)
            acc[i][j] = (floatx4){0.f, 0.f, 0.f, 0.f};

    for (int k0 = 0; k0 < 512; k0 += 32) {
        const int koff = k0 * 16;     // (k0>>3)*128 elems
        half8 ah[4], bh[4];
#pragma unroll
        for (int ti = 0; ti < 4; ti++)
            ah[ti] = *(const half8*)(Ah + ti * 8192 + koff);
#pragma unroll
        for (int tj = 0; tj < 4; tj++)
            bh[tj] = *(const half8*)(Bh + tj * 8192 + koff);
#pragma unroll
        for (int tj = 0; tj < 4; tj++)
#pragma unroll
            for (int ti = 0; ti < 4; ti++)
                acc[ti][tj] = __builtin_amdgcn_mfma_f32_16x16x32_f16(ah[ti], bh[tj], acc[ti][tj], 0, 0, 0);
    }

    // epilogue: D col = lane&15, row = quad*4+reg (m89-verified layout)
#pragma unroll
    for (int tj = 0; tj < 4; tj++) {
        int n = n0 + wn + tj * 16 + l16;
        float bv = bias[n];
#pragma unroll
        for (int ti = 0; ti < 4; ti++) {
#pragma unroll
            for (int r = 0; r < 4; r++) {
                int pos = wm + ti * 16 + quad * 4 + r;
                bool valid = pos < len;
                float v = valid ? (acc[ti][tj][r] + bv) : 0.f;
                out[((size_t)pos * Bmol + mol) * 512 + n] = v;
            }
        }
    }
}

// apairs one-pass gather: winner int4 + bonds gather -> 134 MB write, once.
__device__ __forceinline__ void apairs_body(
    int chunk, const int* __restrict__ winner, const float* __restrict__ bonds,
    const int* __restrict__ a_scope, float* __restrict__ out_ap)
{
    int t = chunk * 256 + threadIdx.x;
    int b = t >> 12;
    int p1 = (t >> 5) & 127;
    int p2q = t & 31;
    int len = a_scope[2 * b + 1];
    const int4 w = ((const int4*)winner)[t];

    int wi0 = w.x, wi1 = w.y, wi2 = w.z, wi3 = w.w;
    float rows[4][16];
#pragma unroll
    for (int c = 0; c < 16; c++) {
        rows[0][c] = 0.f; rows[1][c] = 0.f; rows[2][c] = 0.f; rows[3][c] = 0.f;
    }
    if (wi0 >= 0) {
        const float4* p = (const float4*)(bonds + (size_t)wi0 * 16);
#pragma unroll
        for (int c = 0; c < 4; c++) {
            float4 v = p[c];
            rows[0][4*c+0] = v.x; rows[0][4*c+1] = v.y; rows[0][4*c+2] = v.z; rows[0][4*c+3] = v.w;
        }
    }
    if (wi1 >= 0) {
        const float4* p = (const float4*)(bonds + (size_t)wi1 * 16);
#pragma unroll
        for (int c = 0; c < 4; c++) {
            float4 v = p[c];
            rows[1][4*c+0] = v.x; rows[1][4*c+1] = v.y; rows[1][4*c+2] = v.z; rows[1][4*c+3] = v.w;
        }
    }
    if (wi2 >= 0) {
        const float4* p = (const float4*)(bonds + (size_t)wi2 * 16);
#pragma unroll
        for (int c = 0; c < 4; c++) {
            float4 v = p[c];
            rows[2][4*c+0] = v.x; rows[2][4*c+1] = v.y; rows[2][4*c+2] = v.z; rows[2][4*c+3] = v.w;
        }
    }
    if (wi3 >= 0) {
        const float4* p = (const float4*)(bonds + (size_t)wi3 * 16);
#pragma unroll
        for (int c = 0; c < 4; c++) {
            float4 v = p[c];
            rows[3][4*c+0] = v.x; rows[3][4*c+1] = v.y; rows[3][4*c+2] = v.z; rows[3][4*c+3] = v.w;
        }
    }

    bool iv0 = (p2q * 4 + 0 >= len);
    bool iv1 = (p2q * 4 + 1 >= len);
    bool iv2 = (p2q * 4 + 2 >= len);
    bool iv3 = (p2q * 4 + 3 >= len);
    float* ob = out_ap + ((size_t)b * 16 * 128 + p1) * 128 + p2q * 4;
#pragma unroll
    for (int h = 0; h < 16; h++) {
        float4 v;
        v.x = iv0 ? NEG_BIG : rows[0][h];
        v.y = iv1 ? NEG_BIG : rows[1][h];
        v.z = iv2 ? NEG_BIG : rows[2][h];
        v.w = iv3 ? NEG_BIG : rows[3][h];
        *(float4*)(ob + (size_t)h * 16384) = v;
    }
}

// ================= K1: bonds | A-f16(gather+pad+frag) | W-f16(frag) | scatter | mask =================
__global__ __launch_bounds__(256) void k_phase1(
    const float* __restrict__ fB, const float* __restrict__ fBo,
    const float* __restrict__ Wb_raw, const float* __restrict__ b_bond,
    float* __restrict__ bonds_ws, int Nb,
    const float* __restrict__ fA, const float* __restrict__ fAo,
    short* __restrict__ AHf,
    const float* __restrict__ W, short* __restrict__ WHf,
    const int* __restrict__ b2a, const int* __restrict__ b2revb,
    const int* __restrict__ b_scope, int* __restrict__ winner,
    const int* __restrict__ a_scope, float* __restrict__ mask_out,
    int Bmol, int nBondsB, int nScatB)
{
    __shared__ char smem[33792];
    int bid = blockIdx.x;
    int tid = threadIdx.x;
    if (bid < nBondsB) {
        bonds_body(bid, smem, fB, fBo, Wb_raw, b_bond, bonds_ws, Nb);
        return;
    }
    bid -= nBondsB;
    if (bid < 4096) {
        // A: gather via a_scope, pad to 128 rows, f16 cast, fragment order.
        int t = bid * 256 + tid;
        int l16 = t & 15, kq = (t >> 4) & 63, rt = (t >> 10) & 7, mol = t >> 13;
        int start = a_scope[2 * mol], len = a_scope[2 * mol + 1];
        int row = rt * 16 + l16;
        short8 h8;
#pragma unroll
        for (int e = 0; e < 8; e++) h8[e] = 0;
        if (row < len) {
            int kg = kq * 8;
            const float* p = (kg < 256) ? (fA + (size_t)(start + row) * 256 + kg)
                                        : (fAo + (size_t)(start + row) * 256 + (kg - 256));
            float4 v0 = ((const float4*)p)[0];
            float4 v1 = ((const float4*)p)[1];
            h8[0] = f2h(v0.x); h8[1] = f2h(v0.y); h8[2] = f2h(v0.z); h8[3] = f2h(v0.w);
            h8[4] = f2h(v1.x); h8[5] = f2h(v1.y); h8[6] = f2h(v1.z); h8[7] = f2h(v1.w);
        }
        size_t o = (size_t)mol * 65536 + (size_t)(rt * 64 + kq) * 128 + l16 * 8;
        *(short8*)(AHf + o) = h8;
        return;
    }
    bid -= 4096;
    if (bid < 128) {
        // W: [k][n] fp32 -> fragment-ordered f16
        int t = bid * 256 + tid;
        int l16 = t & 15, kq = (t >> 4) & 63, nt = t >> 10;
        short8 h8;
#pragma unroll
        for (int e = 0; e < 8; e++)
            h8[e] = f2h(W[(size_t)(kq * 8 + e) * 512 + nt * 16 + l16]);
        int o = (nt * 64 + kq) * 128 + l16 * 8;
        *(short8*)(WHf + o) = h8;
        return;
    }
    bid -= 128;
    if (bid < nScatB) {
        scatter_body(bid, smem, b2a, b2revb, b_scope, winner, Nb, Bmol);
        return;
    }
    bid -= nScatB;
    {
        int t = bid * 256 + tid;
        if (t < Bmol * 128) {
            int b = t >> 7, p = t & 127;
            mask_out[t] = (p >= a_scope[2 * b + 1]) ? 1.0f : 0.0f;
        }
    }
}

// ================= K2: zero-LDS f16 atoms staggered with one-pass apairs =================
// block b does 5 jobs: its atoms tile at slot (b&3), and 4 apairs chunks.
// => ~1/4 of blocks on the MFMA pipe while ~3/4 stream the 134 MB write; no smem, no barriers.
__global__ __launch_bounds__(256, 3) void k_phase2(
    const int* __restrict__ a_scope,
    const short* __restrict__ AHf, const short* __restrict__ WHf,
    const float* __restrict__ b_atom,
    const int* __restrict__ winner, const float* __restrict__ bonds_ws,
    float* __restrict__ out_emb, float* __restrict__ out_ap,
    int Bmol)
{
    const int bid = blockIdx.x;          // 0 .. 4*Bmol-1
    const int s = bid & 3;
    int ai = 0;
#pragma unroll
    for (int r = 0; r < 5; r++) {
        if (r == s) {
            atoms_body(bid, a_scope, AHf, WHf, b_atom, out_emb, Bmol);
        } else {
            apairs_body(bid * 4 + ai, winner, bonds_ws, a_scope, out_ap);
            ai++;
        }
    }
}

extern "C" void kernel_launch(void* const* d_in, const int* in_sizes, int n_in,
                              void* d_out, int out_size, void* d_ws, size_t ws_size,
                              hipStream_t stream)
{
    const float* f_atoms     = (const float*)d_in[0];
    const float* f_bonds     = (const float*)d_in[1];
    const float* f_atoms_out = (const float*)d_in[2];
    const float* f_bonds_out = (const float*)d_in[3];
    const int*   b2a         = (const int*)d_in[4];
    const int*   b2revb      = (const int*)d_in[5];
    const int*   a_scope     = (const int*)d_in[6];
    const int*   b_scope     = (const int*)d_in[7];
    const float* W_atom      = (const float*)d_in[9];
    const float* b_atom      = (const float*)d_in[10];
    const float* W_bond      = (const float*)d_in[11];
    const float* b_bond      = (const float*)d_in[12];

    const int Bmol = in_sizes[6] / 2;   // 128
    const int Nb   = in_sizes[4];

    char* ws = (char*)d_ws;
    size_t off = 0;
    float* bonds_ws = (float*)(ws + off); off += ((size_t)Nb * 16 * 4 + 255) & ~(size_t)255;
    int*   winner   = (int*)(ws + off);   off += (size_t)Bmol * 16384 * 4;
    short* WHf      = (short*)(ws + off); off += 512 * 512 * 2;
    short* AHf      = (short*)(ws + off); off += (size_t)Bmol * 65536 * 2;

    float* out_emb  = (float*)d_out;                                // (128, B, 512)
    float* out_ap   = out_emb + (size_t)128 * Bmol * 512;           // (B, 16, 128, 128)
    float* out_mask = out_ap + (size_t)Bmol * 16 * 128 * 128;       // (B, 128)

    // winner = -1 via byte pattern 0xFF (graph-capturable memset node)
    hipMemsetAsync(winner, 0xFF, (size_t)Bmol * 16384 * 4, stream);

    // K1: bonds GEMM | A f16 frag | W f16 frag | scatter | mask
    const int nBondsB = (Nb + 63) / 64;
    const int nScatB  = (Nb + 255) / 256;
    const int nMaskB  = (Bmol * 128 + 255) / 256;
    hipLaunchKernelGGL(k_phase1, dim3(nBondsB + 4096 + 128 + nScatB + nMaskB), dim3(256), 0, stream,
                       f_bonds, f_bonds_out, W_bond, b_bond, bonds_ws, Nb,
                       f_atoms, f_atoms_out, AHf,
                       W_atom, WHf,
                       b2a, b2revb, b_scope, winner,
                       a_scope, out_mask, Bmol, nBondsB, nScatB);

    // K2: zero-LDS f16 atoms GEMM staggered with one-pass apairs gather/write
    hipLaunchKernelGGL(k_phase2, dim3(4 * Bmol), dim3(256), 0, stream,
                       a_scope, AHf, WHf, b_atom,
                       winner, bonds_ws, out_emb, out_ap, Bmol);
}

// Round 8
// 299.445 us; speedup vs baseline: 1.2289x; 1.2289x over previous
//
#include <hip/hip_runtime.h>
#include <math.h>

#define NEG_BIG (-1e30f)

typedef __attribute__((ext_vector_type(8))) short short8;
typedef __attribute__((ext_vector_type(8))) _Float16 half8;
typedef __attribute__((ext_vector_type(4))) float floatx4;

__device__ __forceinline__ unsigned short f2bf(float x) {
    unsigned u = __float_as_uint(x);
    unsigned r = (u + 0x7fffu + ((u >> 16) & 1u)) >> 16;
    return (unsigned short)r;
}
__device__ __forceinline__ short f2h(float x) {
    _Float16 h = (_Float16)x;
    return __builtin_bit_cast(short, h);
}

// ================= bodies =================

// bonds GEMM: 64 bonds/block, 16 heads, K=512, bf16 (proven numerics, unchanged).
__device__ __forceinline__ void bonds_body(
    int bbid, char* smem,
    const float* __restrict__ fB, const float* __restrict__ fBo,
    const float* __restrict__ Wb_raw, const float* __restrict__ bb_,
    float* __restrict__ bonds, int Nb)
{
    short* feat = (short*)smem;              // [64][136]
    short* wb   = (short*)(smem + 17408);    // [16][512] chunk-swizzled

    const int tid = threadIdx.x;
    const int j0 = bbid * 64;

    for (int c = tid; c < 8192; c += 256) {
        int k = c >> 4, h = c & 15;
        wb[h * 512 + ((((k >> 3) + h) & 63) << 3) + (k & 7)] = (short)f2bf(Wb_raw[c]);
    }

    const int wid = tid >> 6, lane = tid & 63;
    const int quad = lane >> 4, l16 = lane & 15;
    floatx4 acc = (floatx4){0.f, 0.f, 0.f, 0.f};

    const int fr = tid >> 2;
    const int fs = (tid & 3) * 32;
    const int j = j0 + fr;

    for (int k0 = 0; k0 < 512; k0 += 128) {
        float x[32];
        if (j < Nb) {
            const float* p = (k0 < 256) ? (fB + (size_t)j * 256 + k0 + fs)
                                        : (fBo + (size_t)j * 256 + (k0 - 256) + fs);
#pragma unroll
            for (int i = 0; i < 8; i++) {
                float4 v = ((const float4*)p)[i];
                x[i * 4 + 0] = v.x; x[i * 4 + 1] = v.y;
                x[i * 4 + 2] = v.z; x[i * 4 + 3] = v.w;
            }
        } else {
#pragma unroll
            for (int i = 0; i < 32; i++) x[i] = 0.f;
        }
        __syncthreads();
#pragma unroll
        for (int c = 0; c < 4; c++) {
            short8 s;
#pragma unroll
            for (int i = 0; i < 8; i++) s[i] = (short)f2bf(x[c * 8 + i]);
            *(short8*)&feat[fr * 136 + fs + c * 8] = s;
        }
        __syncthreads();
#pragma unroll
        for (int kk = 0; kk < 4; kk++) {
            short8 a = *(const short8*)&feat[(wid * 16 + l16) * 136 + kk * 32 + quad * 8];
            int kchunk = (k0 + kk * 32 + quad * 8) >> 3;
            short8 b = *(const short8*)&wb[l16 * 512 + (((kchunk + l16) & 63) * 8)];
            acc = __builtin_amdgcn_mfma_f32_16x16x32_bf16(a, b, acc, 0, 0, 0);
        }
    }
    float bv = bb_[l16];
#pragma unroll
    for (int r = 0; r < 4; r++) {
        int jj = j0 + wid * 16 + quad * 4 + r;
        if (jj < Nb) bonds[(size_t)jj * 16 + l16] = acc[r] + bv;
    }
}

// scatter: last-update-wins via atomicMax (winner pre-set -1 by memset)
__device__ __forceinline__ void scatter_body(
    int sbid, char* smem,
    const int* __restrict__ b2a, const int* __restrict__ b2revb,
    const int* __restrict__ b_scope, int* __restrict__ winner,
    int Nb, int Bmol)
{
    int* sb = (int*)smem;
    int tid = threadIdx.x;
    if (tid < Bmol) sb[tid] = b_scope[2 * tid];
    __syncthreads();
    int j = sbid * 256 + tid;
    if (j >= Nb) return;
    int lo = 0, hi = Bmol;
    while (lo < hi) { int mid = (lo + hi) >> 1; if (sb[mid] <= j) lo = mid + 1; else hi = mid; }
    int mol = lo - 1; if (mol < 0) mol = 0;
    int p2 = b2a[j];
    int p1 = b2a[b2revb[j]];
    atomicMax(&winner[mol * 16384 + p1 * 128 + p2], j);
}

// atoms GEMM, ZERO-LDS, pure-f16 single product.
// Frag chunk layout (A and B): elem (r,k) at [(rt*64+kq)*128 + l16*8 + e],
// r=rt*16+l16, k=kq*8+e. A wave's frag load = one coalesced 1KB dwordx4 per quarter.
__device__ __forceinline__ void atoms_body(
    int abid,
    const int* __restrict__ a_scope,
    const short* __restrict__ AHf, const short* __restrict__ WHf,
    const float* __restrict__ bias, float* __restrict__ out, int Bmol)
{
    const int tid = threadIdx.x;
    const int mol = abid >> 2;
    const int n0 = (abid & 3) * 128;
    const int wid = tid >> 6, lane = tid & 63;
    const int wm = (wid >> 1) * 64, wn = (wid & 1) * 64;
    const int quad = lane >> 4, l16 = lane & 15;
    const int len = a_scope[2 * mol + 1];

    const int laneoff = quad * 128 + l16 * 8;
    const short* __restrict__ Ah = AHf + (size_t)mol * 65536 + (wm >> 4) * 8192 + laneoff;
    const short* __restrict__ Bh = WHf + ((n0 + wn) >> 4) * 8192 + laneoff;

    floatx4 acc[4][4];
#pragma unroll
    for (int i = 0; i < 4; i++)
#pragma unroll
        for (int j = 0; j < 4; j++)
            acc[i][j] = (floatx4){0.f, 0.f, 0.f, 0.f};

    for (int k0 = 0; k0 < 512; k0 += 32) {
        const int koff = k0 * 16;     // (k0>>3)*128 elems
        half8 ah[4], bh[4];
#pragma unroll
        for (int ti = 0; ti < 4; ti++)
            ah[ti] = *(const half8*)(Ah + ti * 8192 + koff);
#pragma unroll
        for (int tj = 0; tj < 4; tj++)
            bh[tj] = *(const half8*)(Bh + tj * 8192 + koff);
#pragma unroll
        for (int tj = 0; tj < 4; tj++)
#pragma unroll
            for (int ti = 0; ti < 4; ti++)
                acc[ti][tj] = __builtin_amdgcn_mfma_f32_16x16x32_f16(ah[ti], bh[tj], acc[ti][tj], 0, 0, 0);
    }

    // epilogue: D col = lane&15, row = quad*4+reg (m89-verified layout)
#pragma unroll
    for (int tj = 0; tj < 4; tj++) {
        int n = n0 + wn + tj * 16 + l16;
        float bv = bias[n];
#pragma unroll
        for (int ti = 0; ti < 4; ti++) {
#pragma unroll
            for (int r = 0; r < 4; r++) {
                int pos = wm + ti * 16 + quad * 4 + r;
                bool valid = pos < len;
                float v = valid ? (acc[ti][tj][r] + bv) : 0.f;
                out[((size_t)pos * Bmol + mol) * 512 + n] = v;
            }
        }
    }
}

// apairs one-pass gather: winner int4 + bonds gather -> 134 MB write, once.
__device__ __forceinline__ void apairs_body(
    int chunk, const int* __restrict__ winner, const float* __restrict__ bonds,
    const int* __restrict__ a_scope, float* __restrict__ out_ap)
{
    int t = chunk * 256 + threadIdx.x;
    int b = t >> 12;
    int p1 = (t >> 5) & 127;
    int p2q = t & 31;
    int len = a_scope[2 * b + 1];
    const int4 w = ((const int4*)winner)[t];

    int wi0 = w.x, wi1 = w.y, wi2 = w.z, wi3 = w.w;
    float rows[4][16];
#pragma unroll
    for (int c = 0; c < 16; c++) {
        rows[0][c] = 0.f; rows[1][c] = 0.f; rows[2][c] = 0.f; rows[3][c] = 0.f;
    }
    if (wi0 >= 0) {
        const float4* p = (const float4*)(bonds + (size_t)wi0 * 16);
#pragma unroll
        for (int c = 0; c < 4; c++) {
            float4 v = p[c];
            rows[0][4*c+0] = v.x; rows[0][4*c+1] = v.y; rows[0][4*c+2] = v.z; rows[0][4*c+3] = v.w;
        }
    }
    if (wi1 >= 0) {
        const float4* p = (const float4*)(bonds + (size_t)wi1 * 16);
#pragma unroll
        for (int c = 0; c < 4; c++) {
            float4 v = p[c];
            rows[1][4*c+0] = v.x; rows[1][4*c+1] = v.y; rows[1][4*c+2] = v.z; rows[1][4*c+3] = v.w;
        }
    }
    if (wi2 >= 0) {
        const float4* p = (const float4*)(bonds + (size_t)wi2 * 16);
#pragma unroll
        for (int c = 0; c < 4; c++) {
            float4 v = p[c];
            rows[2][4*c+0] = v.x; rows[2][4*c+1] = v.y; rows[2][4*c+2] = v.z; rows[2][4*c+3] = v.w;
        }
    }
    if (wi3 >= 0) {
        const float4* p = (const float4*)(bonds + (size_t)wi3 * 16);
#pragma unroll
        for (int c = 0; c < 4; c++) {
            float4 v = p[c];
            rows[3][4*c+0] = v.x; rows[3][4*c+1] = v.y; rows[3][4*c+2] = v.z; rows[3][4*c+3] = v.w;
        }
    }

    bool iv0 = (p2q * 4 + 0 >= len);
    bool iv1 = (p2q * 4 + 1 >= len);
    bool iv2 = (p2q * 4 + 2 >= len);
    bool iv3 = (p2q * 4 + 3 >= len);
    float* ob = out_ap + ((size_t)b * 16 * 128 + p1) * 128 + p2q * 4;
#pragma unroll
    for (int h = 0; h < 16; h++) {
        float4 v;
        v.x = iv0 ? NEG_BIG : rows[0][h];
        v.y = iv1 ? NEG_BIG : rows[1][h];
        v.z = iv2 ? NEG_BIG : rows[2][h];
        v.w = iv3 ? NEG_BIG : rows[3][h];
        *(float4*)(ob + (size_t)h * 16384) = v;
    }
}

// ================= K1: bonds | A-f16(gather+pad+frag) | W-f16(frag) | scatter | mask =================
__global__ __launch_bounds__(256) void k_phase1(
    const float* __restrict__ fB, const float* __restrict__ fBo,
    const float* __restrict__ Wb_raw, const float* __restrict__ b_bond,
    float* __restrict__ bonds_ws, int Nb,
    const float* __restrict__ fA, const float* __restrict__ fAo,
    short* __restrict__ AHf,
    const float* __restrict__ W, short* __restrict__ WHf,
    const int* __restrict__ b2a, const int* __restrict__ b2revb,
    const int* __restrict__ b_scope, int* __restrict__ winner,
    const int* __restrict__ a_scope, float* __restrict__ mask_out,
    int Bmol, int nBondsB, int nScatB)
{
    __shared__ char smem[33792];
    int bid = blockIdx.x;
    int tid = threadIdx.x;
    if (bid < nBondsB) {
        bonds_body(bid, smem, fB, fBo, Wb_raw, b_bond, bonds_ws, Nb);
        return;
    }
    bid -= nBondsB;
    if (bid < 4096) {
        // A: gather via a_scope, pad to 128 rows, f16 cast, fragment order.
        int t = bid * 256 + tid;
        int l16 = t & 15, kq = (t >> 4) & 63, rt = (t >> 10) & 7, mol = t >> 13;
        int start = a_scope[2 * mol], len = a_scope[2 * mol + 1];
        int row = rt * 16 + l16;
        short8 h8;
#pragma unroll
        for (int e = 0; e < 8; e++) h8[e] = 0;
        if (row < len) {
            int kg = kq * 8;
            const float* p = (kg < 256) ? (fA + (size_t)(start + row) * 256 + kg)
                                        : (fAo + (size_t)(start + row) * 256 + (kg - 256));
            float4 v0 = ((const float4*)p)[0];
            float4 v1 = ((const float4*)p)[1];
            h8[0] = f2h(v0.x); h8[1] = f2h(v0.y); h8[2] = f2h(v0.z); h8[3] = f2h(v0.w);
            h8[4] = f2h(v1.x); h8[5] = f2h(v1.y); h8[6] = f2h(v1.z); h8[7] = f2h(v1.w);
        }
        size_t o = (size_t)mol * 65536 + (size_t)(rt * 64 + kq) * 128 + l16 * 8;
        *(short8*)(AHf + o) = h8;
        return;
    }
    bid -= 4096;
    if (bid < 128) {
        // W: [k][n] fp32 -> fragment-ordered f16
        int t = bid * 256 + tid;
        int l16 = t & 15, kq = (t >> 4) & 63, nt = t >> 10;
        short8 h8;
#pragma unroll
        for (int e = 0; e < 8; e++)
            h8[e] = f2h(W[(size_t)(kq * 8 + e) * 512 + nt * 16 + l16]);
        int o = (nt * 64 + kq) * 128 + l16 * 8;
        *(short8*)(WHf + o) = h8;
        return;
    }
    bid -= 128;
    if (bid < nScatB) {
        scatter_body(bid, smem, b2a, b2revb, b_scope, winner, Nb, Bmol);
        return;
    }
    bid -= nScatB;
    {
        int t = bid * 256 + tid;
        if (t < Bmol * 128) {
            int b = t >> 7, p = t & 127;
            mask_out[t] = (p >= a_scope[2 * b + 1]) ? 1.0f : 0.0f;
        }
    }
}

// ================= K2: one job per block, atoms interleaved 1:4 among apairs =================
// grid = 5*nAtomsB = 2560. bid%5==0 -> atoms(bid/5); else -> apairs(bid/5*4 + bid%5 - 1).
// Dispatch-order interleave keeps a ~1:4 compute:memory block mix on every CU at all times;
// one job per block restores TLP (grid no longer caps occupancy at 2 blocks/CU).
__global__ __launch_bounds__(256, 4) void k_phase2(
    const int* __restrict__ a_scope,
    const short* __restrict__ AHf, const short* __restrict__ WHf,
    const float* __restrict__ b_atom,
    const int* __restrict__ winner, const float* __restrict__ bonds_ws,
    float* __restrict__ out_emb, float* __restrict__ out_ap,
    int Bmol)
{
    const int bid = blockIdx.x;
    const int g = bid / 5, r = bid % 5;
    if (r == 0) {
        atoms_body(g, a_scope, AHf, WHf, b_atom, out_emb, Bmol);
    } else {
        apairs_body(g * 4 + (r - 1), winner, bonds_ws, a_scope, out_ap);
    }
}

extern "C" void kernel_launch(void* const* d_in, const int* in_sizes, int n_in,
                              void* d_out, int out_size, void* d_ws, size_t ws_size,
                              hipStream_t stream)
{
    const float* f_atoms     = (const float*)d_in[0];
    const float* f_bonds     = (const float*)d_in[1];
    const float* f_atoms_out = (const float*)d_in[2];
    const float* f_bonds_out = (const float*)d_in[3];
    const int*   b2a         = (const int*)d_in[4];
    const int*   b2revb      = (const int*)d_in[5];
    const int*   a_scope     = (const int*)d_in[6];
    const int*   b_scope     = (const int*)d_in[7];
    const float* W_atom      = (const float*)d_in[9];
    const float* b_atom      = (const float*)d_in[10];
    const float* W_bond      = (const float*)d_in[11];
    const float* b_bond      = (const float*)d_in[12];

    const int Bmol = in_sizes[6] / 2;   // 128
    const int Nb   = in_sizes[4];

    char* ws = (char*)d_ws;
    size_t off = 0;
    float* bonds_ws = (float*)(ws + off); off += ((size_t)Nb * 16 * 4 + 255) & ~(size_t)255;
    int*   winner   = (int*)(ws + off);   off += (size_t)Bmol * 16384 * 4;
    short* WHf      = (short*)(ws + off); off += 512 * 512 * 2;
    short* AHf      = (short*)(ws + off); off += (size_t)Bmol * 65536 * 2;

    float* out_emb  = (float*)d_out;                                // (128, B, 512)
    float* out_ap   = out_emb + (size_t)128 * Bmol * 512;           // (B, 16, 128, 128)
    float* out_mask = out_ap + (size_t)Bmol * 16 * 128 * 128;       // (B, 128)

    // winner = -1 via byte pattern 0xFF (graph-capturable memset node)
    hipMemsetAsync(winner, 0xFF, (size_t)Bmol * 16384 * 4, stream);

    // K1: bonds GEMM | A f16 frag | W f16 frag | scatter | mask
    const int nBondsB = (Nb + 63) / 64;
    const int nScatB  = (Nb + 255) / 256;
    const int nMaskB  = (Bmol * 128 + 255) / 256;
    hipLaunchKernelGGL(k_phase1, dim3(nBondsB + 4096 + 128 + nScatB + nMaskB), dim3(256), 0, stream,
                       f_bonds, f_bonds_out, W_bond, b_bond, bonds_ws, Nb,
                       f_atoms, f_atoms_out, AHf,
                       W_atom, WHf,
                       b2a, b2revb, b_scope, winner,
                       a_scope, out_mask, Bmol, nBondsB, nScatB);

    // K2: atoms (1 of 5) interleaved with apairs (4 of 5), one job per block
    const int nAtomsB = 4 * Bmol;                 // 512
    hipLaunchKernelGGL(k_phase2, dim3(5 * nAtomsB), dim3(256), 0, stream,
                       a_scope, AHf, WHf, b_atom,
                       winner, bonds_ws, out_emb, out_ap, Bmol);
}